// Round 3
// baseline (156.859 us; speedup 1.0000x reference)
//
#include <hip/hip_runtime.h>
#include <hip/hip_bf16.h>
#include <math.h>

// Problem dims (fixed by reference)
#define BB 8
#define SS 8192
#define VV 64
#define AGG_OUT 224   // D - DV

// ---- workspace layout (float/int32 slots, 4B each) ----
#define WS_FLAGS 0          // [0]=floatmode(1=bf16,0=f32) [1]=maskmode(0=i32,1=f32,2=bf16,3=u8)
#define WS_A     16         // a[224]
#define WS_C     240
#define WS_D     464
#define WS_AQ    688        // aq/cq/dq0 [256] each
#define WS_CQ    944
#define WS_DQ    1200
#define WS_AK    1456       // ak/ck/dk [256] (dk includes bk)
#define WS_CK    1712
#define WS_DK    1968
#define WS_AV    2224       // av/cv/dv [256] (dv includes bv)
#define WS_CV    2480
#define WS_DV    2736
#define WS_WQE   2992       // var_emb @ wq[0:32,:]  [64*256]
#define WS_WKE   19376
#define WS_WVE   35760
#define WS_CSUM  52144      // [8*256] ctx accumulator (empty-variate path adds here)
#define WS_BINS  54192      // [8*64*24] (b*64+v)*24 + h*3 + {W,WV,WT}  (zeroed in K1)
#define WS_COEF  66480      // [8*64*8*4] (bv*8+h)*4 + {A,B,C,m}  (log2e-scaled, atomicExch'd)
#define WS_SP    82864      // [64 slices * 64 v * 8] stats partials
#define WS_ACC   117696     // acc[8] scalar partials (unused this version, kept zeroed)
#define WS_CNT   117704     // [8] per-b coef tickets (zeroed in K1)

__device__ __forceinline__ float ldf(const void* p, int idx, int fm) {
  if (fm) {
    unsigned int u = ((const unsigned short*)p)[idx];
    return __uint_as_float(u << 16);
  }
  return ((const float*)p)[idx];
}

__device__ __forceinline__ bool mask_at(const void* p, int idx, int mm) {
  switch (mm) {
    case 0: return ((const int*)p)[idx] != 0;
    case 1: return ((const float*)p)[idx] != 0.0f;
    case 2: return ((const unsigned short*)p)[idx] != 0;
    default: return ((const unsigned char*)p)[idx] != 0;
  }
}

// order-preserving float<->uint key (for atomicMin/Max on LDS uints)
__device__ __forceinline__ unsigned int fkey(float f) {
  unsigned int u = __float_as_uint(f);
  return (u & 0x80000000u) ? ~u : (u | 0x80000000u);
}
__device__ __forceinline__ float funkey(unsigned int k) {
  unsigned int u = (k & 0x80000000u) ? (k ^ 0x80000000u) : ~k;
  return __uint_as_float(u);
}

__device__ __forceinline__ int detect_fm_block(const void* times) {
  __shared__ int cntR;
  int tid = threadIdx.x;
  if (tid == 0) cntR = 0;
  __syncthreads();
  const unsigned int* tw = (const unsigned int*)times;
  int local = 0;
  for (int i = tid; i < 1024; i += 256) {
    unsigned int lo = tw[i] & 0xFFFFu;
    if (lo >= 0x3800u && lo < 0x3F80u) local++;   // bf16 pattern of U(0,1)
  }
  atomicAdd(&cntR, local);
  __syncthreads();
  int r = (cntR > 512) ? 1 : 0;
  __syncthreads();
  return r;
}

__device__ __forceinline__ int detect_mm_block(const void* mask) {
  __shared__ int f01, ff32, fbf;
  int tid = threadIdx.x;
  if (tid == 0) { f01 = 1; ff32 = 1; fbf = 1; }
  __syncthreads();
  const unsigned int* mw = (const unsigned int*)mask;
  int l01 = 1, lf32 = 1, lbf = 1;
  for (int i = tid; i < 2048; i += 256) {
    unsigned int w = mw[i];
    if (w > 1u) l01 = 0;
    if (!(w == 0u || w == 0x3F800000u)) lf32 = 0;
    unsigned int h0 = w & 0xFFFFu, h1 = w >> 16;
    if (!((h0 == 0u || h0 == 0x3F80u) && (h1 == 0u || h1 == 0x3F80u))) lbf = 0;
  }
  if (!l01) atomicAnd(&f01, 0);
  if (!lf32) atomicAnd(&ff32, 0);
  if (!lbf) atomicAnd(&fbf, 0);
  __syncthreads();
  int r = f01 ? 0 : (ff32 ? 1 : (fbf ? 2 : 3));
  __syncthreads();
  return r;
}

// K1: blocks 0..223 acd-collapse; 224..287 per-(b,chunk) segment stats histograms;
//     288..295 zero CSUM+BINS (+ACC+tickets); blk 288 publishes flags.
__global__ void __launch_bounds__(256) k_front(const void* times, const void* values,
                                               const int* fids, const void* mask,
                                               const void* me_w, const void* me_b,
                                               const void* time_w, const void* time_b,
                                               const void* agg_w, const void* agg_b,
                                               float* ws) {
  int blk = blockIdx.x, tid = threadIdx.x;
  if (blk < 224) {
    int fm = detect_fm_block(times);
    int j = blk, i = tid;
    float w0 = ldf(agg_w, i * AGG_OUT + j, fm);
    float w1 = ldf(agg_w, (256 + i) * AGG_OUT + j, fm);
    float sa = ldf(me_w, i, fm) * w0;
    float sc = ldf(time_w, i, fm) * w1;
    float sd = ldf(me_b, i, fm) * w0 + ldf(time_b, i, fm) * w1;
    #pragma unroll
    for (int off = 32; off >= 1; off >>= 1) {
      sa += __shfl_xor(sa, off);
      sc += __shfl_xor(sc, off);
      sd += __shfl_xor(sd, off);
    }
    __shared__ float r[3][4];
    int wid = i >> 6;
    if ((i & 63) == 0) { r[0][wid] = sa; r[1][wid] = sc; r[2][wid] = sd; }
    __syncthreads();
    if (i == 0) {
      ws[WS_A + j] = r[0][0] + r[0][1] + r[0][2] + r[0][3];
      ws[WS_C + j] = r[1][0] + r[1][1] + r[1][2] + r[1][3];
      ws[WS_D + j] = r[2][0] + r[2][1] + r[2][2] + r[2][3] + ldf(agg_b, j, fm);
    }
  } else if (blk < 288) {
    int fm = detect_fm_block(times);
    int mm = detect_mm_block(mask);
    int sblk = blk - 224, b = sblk >> 3, chunk = sblk & 7;
    __shared__ float hc[64], hsv[64], hst[64];
    __shared__ unsigned int hvn[64], hvx[64], htn[64], htx[64];
    if (tid < 64) {
      hc[tid] = 0.f; hsv[tid] = 0.f; hst[tid] = 0.f;
      hvn[tid] = 0xFFFFFFFFu; hvx[tid] = 0u;
      htn[tid] = 0xFFFFFFFFu; htx[tid] = 0u;
    }
    __syncthreads();
    #pragma unroll
    for (int k = 0; k < 4; k++) {
      int idx = b * SS + chunk * 1024 + k * 256 + tid;
      if (mask_at(mask, idx, mm)) {
        int f = fids[idx];
        float val = ldf(values, idx, fm), tim = ldf(times, idx, fm);
        atomicAdd(&hc[f], 1.0f);
        atomicAdd(&hsv[f], val);
        atomicAdd(&hst[f], tim);
        unsigned int vk = fkey(val), tk = fkey(tim);
        atomicMin(&hvn[f], vk); atomicMax(&hvx[f], vk);
        atomicMin(&htn[f], tk); atomicMax(&htx[f], tk);
      }
    }
    __syncthreads();
    if (tid < 64) {
      int base = WS_SP + (sblk * 64 + tid) * 8;
      ws[base + 0] = hc[tid];
      ws[base + 1] = hsv[tid];
      ws[base + 2] = hst[tid];
      ((unsigned int*)ws)[base + 3] = hvn[tid];
      ((unsigned int*)ws)[base + 4] = hvx[tid];
      ((unsigned int*)ws)[base + 5] = htn[tid];
      ((unsigned int*)ws)[base + 6] = htx[tid];
    }
  } else {
    int zblk = blk - 288;
    for (int i = zblk * 256 + tid; i < 14336; i += 2048) ws[WS_CSUM + i] = 0.f;
    if (zblk == 1 && tid < 16) ws[WS_ACC + tid] = 0.f;   // acc[8] + tickets[8]
    if (zblk == 0) {
      int fm = detect_fm_block(times);
      int mm = detect_mm_block(mask);
      if (tid == 0) { ((int*)ws)[0] = fm; ((int*)ws)[1] = mm; }
    }
  }
}

// K2: fold a/c/d through wq/wk/wv (24 blocks) + embedding tables (192 blocks).
__global__ void __launch_bounds__(256) k_pre(const void* wq, const void* wk,
                                             const void* wv, const void* bk,
                                             const void* bv, const void* var_emb,
                                             float* ws) {
  int fm = ((const int*)ws)[0];
  int blk = blockIdx.x, tid = threadIdx.x;
  if (blk < 24) {
    int X = blk >> 3, dg = blk & 7;
    const void* w = (X == 0) ? wq : (X == 1) ? wk : wv;
    __shared__ float sha[224], shc[224], shd[224];
    if (tid < 224) {
      sha[tid] = ws[WS_A + tid];
      shc[tid] = ws[WS_C + tid];
      shd[tid] = ws[WS_D + tid];
    }
    __syncthreads();
    int dsub = tid & 31, jg = tid >> 5;
    int d = dg * 32 + dsub;
    float sa = 0.f, sc = 0.f, sd = 0.f;
    #pragma unroll 4
    for (int jj = 0; jj < 28; jj++) {
      int j = jg * 28 + jj;
      float ww = ldf(w, (32 + j) * 256 + d, fm);
      sa += sha[j] * ww; sc += shc[j] * ww; sd += shd[j] * ww;
    }
    __shared__ float ps[3][8][32];
    ps[0][jg][dsub] = sa; ps[1][jg][dsub] = sc; ps[2][jg][dsub] = sd;
    __syncthreads();
    if (tid < 32) {
      float ra = 0.f, rc = 0.f, rd = 0.f;
      #pragma unroll
      for (int g = 0; g < 8; g++) {
        ra += ps[0][g][tid]; rc += ps[1][g][tid]; rd += ps[2][g][tid];
      }
      int dd = dg * 32 + tid;
      if (X == 1) rd += ldf(bk, dd, fm);
      if (X == 2) rd += ldf(bv, dd, fm);
      int base = (X == 0) ? WS_AQ : (X == 1) ? WS_AK : WS_AV;
      ws[base + dd] = ra;
      ws[base + 256 + dd] = rc;
      ws[base + 512 + dd] = rd;
    }
  } else {
    int idx = blk - 24, X = idx >> 6, v = idx & 63, d = tid;
    const void* w = (X == 0) ? wq : (X == 1) ? wk : wv;
    float s = 0.f;
    #pragma unroll 8
    for (int i = 0; i < 32; i++)
      s += ldf(var_emb, v * 32 + i, fm) * ldf(w, i * 256 + d, fm);
    int base = (X == 0) ? WS_WQE : (X == 1) ? WS_WKE : WS_WVE;
    ws[base + v * 256 + d] = s;
  }
}

// K3+K4 merged (k_cacc): 640 blocks.
//   blocks 0..511  = coef part (v0 k_coef math, verbatim): publish COEF via
//                    atomicExch (L3-coherent), then s_waitcnt(0) + per-b ticket.
//   blocks 512..639 = accum part (v0 k_accum): spin on ticket[b]==64 (tid0 only,
//                    s_sleep), RMW-read COEF into LDS, then the scan.
// All 640 blocks (256 thr, ~16KB LDS) are trivially co-resident on 256 CUs, so
// the spin is deadlock-free regardless of dispatch order.
__global__ void __launch_bounds__(256) k_cacc(const void* values, const void* times,
                                              const int* fids, const void* mask,
                                              const void* bq, float* ws) {
  int fm = ((const int*)ws)[0];
  int blk = blockIdx.x, tid = threadIdx.x;
  unsigned int* ticket = (unsigned int*)(ws + WS_CNT);
  if (blk < 512) {
    int bv = blk, b = bv >> 6, v = bv & 63;
    int h = tid >> 5;
    __shared__ float sp[8][8];
    if (tid < 64) {
      int sl = tid >> 3, c = tid & 7;
      sp[sl][c] = ws[WS_SP + ((b * 8 + sl) * 64 + v) * 8 + c];
    }
    __syncthreads();
    float cT = 0.f, svT = 0.f, stT = 0.f;
    unsigned int vnk = 0xFFFFFFFFu, vxk = 0u, tnk = 0xFFFFFFFFu, txk = 0u;
    #pragma unroll
    for (int sl = 0; sl < 8; sl++) {
      cT += sp[sl][0]; svT += sp[sl][1]; stT += sp[sl][2];
      unsigned int a3 = __float_as_uint(sp[sl][3]);
      unsigned int a4 = __float_as_uint(sp[sl][4]);
      unsigned int a5 = __float_as_uint(sp[sl][5]);
      unsigned int a6 = __float_as_uint(sp[sl][6]);
      vnk = min(vnk, a3); vxk = max(vxk, a4);
      tnk = min(tnk, a5); txk = max(txk, a6);
    }
    if (cT == 0.f) {
      // kpm unmasks position 0 -> attn=1 at s=0 -> ctx = v(s=0)
      int f0 = fids[b * SS];
      float v0 = ldf(values, b * SS, fm), t0 = ldf(times, b * SS, fm);
      float ctx = ws[WS_WVE + f0 * 256 + tid] + ws[WS_DV + tid]
                + v0 * ws[WS_AV + tid] + t0 * ws[WS_CV + tid];
      atomicAdd(&ws[WS_CSUM + b * 256 + tid], ctx);
    } else {
      float inv = 1.0f / cT, mv = svT * inv, mt = stT * inv;
      float qv = ldf(bq, tid, fm) + ws[WS_WQE + v * 256 + tid]
               + mv * ws[WS_AQ + tid] + mt * ws[WS_CQ + tid] + ws[WS_DQ + tid];
      qv *= 0.17677669529663687f * 1.4426950408889634f;  // 1/sqrt(32) * log2(e)
      float pA = qv * (ws[WS_WKE + v * 256 + tid] + ws[WS_DK + tid]);
      float pB = qv * ws[WS_AK + tid];
      float pC = qv * ws[WS_CK + tid];
      #pragma unroll
      for (int off = 16; off >= 1; off >>= 1) {
        pA += __shfl_xor(pA, off);
        pB += __shfl_xor(pB, off);
        pC += __shfl_xor(pC, off);
      }
      if ((tid & 31) == 0) {
        float vmn = funkey(vnk), vmx = funkey(vxk);
        float tmn = funkey(tnk), tmx = funkey(txk);
        float m = pA + fmaxf(pB * vmn, pB * vmx) + fmaxf(pC * tmn, pC * tmx);
        int base = WS_COEF + (bv * 8 + h) * 4;
        atomicExch(&ws[base + 0], pA);
        atomicExch(&ws[base + 1], pB);
        atomicExch(&ws[base + 2], pC);
        atomicExch(&ws[base + 3], m);
      }
    }
    __builtin_amdgcn_s_waitcnt(0);   // drain this wave's atomics to coherence point
    __syncthreads();                  // all waves drained
    if (tid == 0) atomicAdd(&ticket[b], 1u);
  } else {
    int mm = ((const int*)ws)[1];
    int ab = blk - 512;
    int b = ab >> 4, chunk = ab & 15;
    __shared__ float co[64 * 36];    // padded: v*36 + h*4 + c
    __shared__ float bins[64 * 25];  // padded: v*25 + h*3 + c
    for (int i = tid; i < 1600; i += 256) bins[i] = 0.f;
    if (tid == 0) {
      while (atomicAdd(&ticket[b], 0u) < 64u) { __builtin_amdgcn_s_sleep(8); }
    }
    __syncthreads();
    // coherent RMW read of COEF (published by coef blocks via atomicExch)
    for (int i = tid; i < 2048; i += 256) {
      int v = i >> 5, r = i & 31;
      co[v * 36 + r] = atomicAdd(&ws[WS_COEF + b * 2048 + i], 0.0f);
    }
    __syncthreads();
    #pragma unroll
    for (int k = 0; k < 2; k++) {
      int idx = b * SS + chunk * 512 + k * 256 + tid;
      if (mask_at(mask, idx, mm)) {
        int f = fids[idx];
        float val = ldf(values, idx, fm), tim = ldf(times, idx, fm);
        #pragma unroll
        for (int h = 0; h < 8; h++) {
          int cb = f * 36 + h * 4;
          float w = exp2f(co[cb] + val * co[cb + 1] + tim * co[cb + 2] - co[cb + 3]);
          int bb = f * 25 + h * 3;
          atomicAdd(&bins[bb], w);
          atomicAdd(&bins[bb + 1], w * val);
          atomicAdd(&bins[bb + 2], w * tim);
        }
      }
    }
    __syncthreads();
    for (int i = tid; i < 1536; i += 256) {
      int f = i / 24, r = i - f * 24;
      float x = bins[f * 25 + r];
      if (x != 0.f) atomicAdd(&ws[WS_BINS + b * 1536 + i], x);
    }
  }
}

// K5 (k_fin): v0 verbatim — 8 blocks x 1024, per-b full wo/cw1 read.
__global__ void __launch_bounds__(1024) k_fin(const void* wo, const void* bo,
                                              const void* cw1, const void* cb1,
                                              const void* cw2, const void* cb2,
                                              float* ws, void* out) {
  int fm = ((const int*)ws)[0];
  int b = blockIdx.x, tid = threadIdx.x;
  __shared__ float aa[64][9], tt[64][9], ne[64];
  __shared__ float ps[4][256], cs[256], fv[256], pr[16];
  if (tid < 512) {
    int v = tid >> 3, h = tid & 7;
    int base = WS_BINS + b * 1536 + v * 24 + h * 3;
    float W = ws[base], WV = ws[base + 1], WT = ws[base + 2];
    float iW = (W > 0.f) ? 1.0f / W : 0.f;
    aa[v][h] = WV * iW; tt[v][h] = WT * iW;
    if (h == 0) ne[v] = (W > 0.f) ? 1.f : 0.f;
  }
  __syncthreads();
  int d = tid & 255, vg = tid >> 8, h = d >> 5;
  float accP = 0.f, accA = 0.f, accT = 0.f, accN = 0.f;
  #pragma unroll 4
  for (int k = 0; k < 16; k++) {
    int v = vg * 16 + k;
    float nef = ne[v];
    accP += nef * ws[WS_WVE + v * 256 + d];
    accA += aa[v][h];    // zero for empty v
    accT += tt[v][h];
    accN += nef;
  }
  ps[vg][d] = accP + accN * ws[WS_DV + d] + accA * ws[WS_AV + d] + accT * ws[WS_CV + d];
  __syncthreads();
  if (tid < 256)
    cs[tid] = (ws[WS_CSUM + b * 256 + tid] + ps[0][tid] + ps[1][tid]
             + ps[2][tid] + ps[3][tid]) * (1.0f / 64.0f);
  __syncthreads();
  float s = 0.f;
  #pragma unroll 8
  for (int k = 0; k < 64; k++) {
    int i = vg * 64 + k;
    s += cs[i] * ldf(wo, i * 256 + d, fm);
  }
  ps[vg][d] = s;
  __syncthreads();
  if (tid < 256) fv[tid] = ps[0][tid] + ps[1][tid] + ps[2][tid] + ps[3][tid]
                         + ldf(bo, tid, fm);
  __syncthreads();
  float t2 = 0.f;
  #pragma unroll 8
  for (int k = 0; k < 64; k++) {
    int i = vg * 64 + k;
    t2 += fv[i] * ldf(cw1, i * 256 + d, fm);
  }
  ps[vg][d] = t2;
  __syncthreads();
  float p = 0.f;
  if (tid < 256) {
    float t = ps[0][tid] + ps[1][tid] + ps[2][tid] + ps[3][tid] + ldf(cb1, tid, fm);
    t = fmaxf(t, 0.f);
    p = t * ldf(cw2, tid, fm);
  }
  #pragma unroll
  for (int off = 32; off >= 1; off >>= 1) p += __shfl_xor(p, off);
  if ((tid & 63) == 0) pr[tid >> 6] = p;
  __syncthreads();
  if (tid == 0) {
    float o = ldf(cb2, 0, fm);
    #pragma unroll
    for (int wgi = 0; wgi < 16; wgi++) o += pr[wgi];
    if (fm) {
      unsigned int x = __float_as_uint(o);
      unsigned int r = (x + 0x7FFFu + ((x >> 16) & 1u)) >> 16;  // RNE
      ((unsigned short*)out)[b] = (unsigned short)r;
    } else {
      ((float*)out)[b] = o;
    }
  }
}

extern "C" void kernel_launch(void* const* d_in, const int* in_sizes, int n_in,
                              void* d_out, int out_size, void* d_ws, size_t ws_size,
                              hipStream_t stream) {
  const void* times   = d_in[0];
  const int*  fids    = (const int*)d_in[1];
  const void* values  = d_in[2];
  const void* vmask   = d_in[3];
  const void* me_w    = d_in[4];
  const void* me_b    = d_in[5];
  const void* var_emb = d_in[6];
  const void* time_w  = d_in[7];
  const void* time_b  = d_in[8];
  const void* agg_w   = d_in[9];
  const void* agg_b   = d_in[10];
  const void* wq = d_in[11]; const void* bq = d_in[12];
  const void* wk = d_in[13]; const void* bk = d_in[14];
  const void* wv = d_in[15]; const void* bv = d_in[16];
  const void* wo = d_in[17]; const void* bo = d_in[18];
  const void* cw1 = d_in[19]; const void* cb1 = d_in[20];
  const void* cw2 = d_in[21]; const void* cb2 = d_in[22];
  float* ws = (float*)d_ws;

  k_front<<<296, 256, 0, stream>>>(times, values, fids, vmask,
                                   me_w, me_b, time_w, time_b, agg_w, agg_b, ws);
  k_pre<<<216, 256, 0, stream>>>(wq, wk, wv, bk, bv, var_emb, ws);
  k_cacc<<<640, 256, 0, stream>>>(values, times, fids, vmask, bq, ws);
  k_fin<<<8, 1024, 0, stream>>>(wo, bo, cw1, cb1, cw2, cb2, ws, d_out);
}

// Round 4
// 142.052 us; speedup vs baseline: 1.1042x; 1.1042x over previous
//
#include <hip/hip_runtime.h>
#include <hip/hip_bf16.h>
#include <math.h>

// Problem dims (fixed by reference)
#define BB 8
#define SS 8192
#define VV 64
#define AGG_OUT 224   // D - DV

// ---- workspace layout (float/int32 slots, 4B each) ----
#define WS_FLAGS 0          // [0]=floatmode(1=bf16,0=f32) [1]=maskmode(0=i32,1=f32,2=bf16,3=u8)
#define WS_A     16         // a[224]
#define WS_C     240
#define WS_D     464
#define WS_AQ    688        // aq/cq/dq0 [256] each
#define WS_CQ    944
#define WS_DQ    1200
#define WS_AK    1456       // ak/ck/dk [256] (dk includes bk)
#define WS_CK    1712
#define WS_DK    1968
#define WS_AV    2224       // av/cv/dv [256] (dv includes bv)
#define WS_CV    2480
#define WS_DV    2736
#define WS_WQE   2992       // var_emb @ wq[0:32,:]  [64*256]
#define WS_WKE   19376
#define WS_WVE   35760
#define WS_CSUM  52144      // [8*256] ctx accumulator (empty-variate path adds here)
#define WS_BINS  54192      // [8*64*24] (b*64+v)*24 + h*3 + {W,WV,WT}  (zeroed in K1)
#define WS_COEF  66480      // [8*64*8*4] (bv*8+h)*4 + {A,B,C,m}  (log2e-scaled)
#define WS_SP    82864      // [128 slices * 64 v * 8] stats partials (16 chunks per b)
#define WS_ACC   148416     // acc[8] (unused; kept zeroed)
#define WS_CNT   148424     // [8] (unused; kept zeroed)

__device__ __forceinline__ float ldf(const void* p, int idx, int fm) {
  if (fm) {
    unsigned int u = ((const unsigned short*)p)[idx];
    return __uint_as_float(u << 16);
  }
  return ((const float*)p)[idx];
}

__device__ __forceinline__ bool mask_at(const void* p, int idx, int mm) {
  switch (mm) {
    case 0: return ((const int*)p)[idx] != 0;
    case 1: return ((const float*)p)[idx] != 0.0f;
    case 2: return ((const unsigned short*)p)[idx] != 0;
    default: return ((const unsigned char*)p)[idx] != 0;
  }
}

// order-preserving float<->uint key (for atomicMin/Max on LDS uints)
__device__ __forceinline__ unsigned int fkey(float f) {
  unsigned int u = __float_as_uint(f);
  return (u & 0x80000000u) ? ~u : (u | 0x80000000u);
}
__device__ __forceinline__ float funkey(unsigned int k) {
  unsigned int u = (k & 0x80000000u) ? (k ^ 0x80000000u) : ~k;
  return __uint_as_float(u);
}

__device__ __forceinline__ int detect_fm_block(const void* times) {
  __shared__ int cntR;
  int tid = threadIdx.x;
  if (tid == 0) cntR = 0;
  __syncthreads();
  const unsigned int* tw = (const unsigned int*)times;
  int local = 0;
  for (int i = tid; i < 1024; i += 256) {
    unsigned int lo = tw[i] & 0xFFFFu;
    if (lo >= 0x3800u && lo < 0x3F80u) local++;   // bf16 pattern of U(0,1)
  }
  atomicAdd(&cntR, local);
  __syncthreads();
  int r = (cntR > 512) ? 1 : 0;
  __syncthreads();
  return r;
}

__device__ __forceinline__ int detect_mm_block(const void* mask) {
  __shared__ int f01, ff32, fbf;
  int tid = threadIdx.x;
  if (tid == 0) { f01 = 1; ff32 = 1; fbf = 1; }
  __syncthreads();
  const unsigned int* mw = (const unsigned int*)mask;
  int l01 = 1, lf32 = 1, lbf = 1;
  for (int i = tid; i < 2048; i += 256) {
    unsigned int w = mw[i];
    if (w > 1u) l01 = 0;
    if (!(w == 0u || w == 0x3F800000u)) lf32 = 0;
    unsigned int h0 = w & 0xFFFFu, h1 = w >> 16;
    if (!((h0 == 0u || h0 == 0x3F80u) && (h1 == 0u || h1 == 0x3F80u))) lbf = 0;
  }
  if (!l01) atomicAnd(&f01, 0);
  if (!lf32) atomicAnd(&ff32, 0);
  if (!lbf) atomicAnd(&fbf, 0);
  __syncthreads();
  int r = f01 ? 0 : (ff32 ? 1 : (fbf ? 2 : 3));
  __syncthreads();
  return r;
}

// K1: blocks 0..223 acd-collapse; 224..351 per-(b,chunk) segment stats (16 chunks/b,
//     512 elems each — doubled occupancy vs 8 chunks); 352..359 zero CSUM+BINS(+ACC/CNT);
//     blk 352 publishes flags.
__global__ void __launch_bounds__(256) k_front(const void* times, const void* values,
                                               const int* fids, const void* mask,
                                               const void* me_w, const void* me_b,
                                               const void* time_w, const void* time_b,
                                               const void* agg_w, const void* agg_b,
                                               float* ws) {
  int blk = blockIdx.x, tid = threadIdx.x;
  if (blk < 224) {
    int fm = detect_fm_block(times);
    int j = blk, i = tid;
    float w0 = ldf(agg_w, i * AGG_OUT + j, fm);
    float w1 = ldf(agg_w, (256 + i) * AGG_OUT + j, fm);
    float sa = ldf(me_w, i, fm) * w0;
    float sc = ldf(time_w, i, fm) * w1;
    float sd = ldf(me_b, i, fm) * w0 + ldf(time_b, i, fm) * w1;
    #pragma unroll
    for (int off = 32; off >= 1; off >>= 1) {
      sa += __shfl_xor(sa, off);
      sc += __shfl_xor(sc, off);
      sd += __shfl_xor(sd, off);
    }
    __shared__ float r[3][4];
    int wid = i >> 6;
    if ((i & 63) == 0) { r[0][wid] = sa; r[1][wid] = sc; r[2][wid] = sd; }
    __syncthreads();
    if (i == 0) {
      ws[WS_A + j] = r[0][0] + r[0][1] + r[0][2] + r[0][3];
      ws[WS_C + j] = r[1][0] + r[1][1] + r[1][2] + r[1][3];
      ws[WS_D + j] = r[2][0] + r[2][1] + r[2][2] + r[2][3] + ldf(agg_b, j, fm);
    }
  } else if (blk < 352) {
    int fm = detect_fm_block(times);
    int mm = detect_mm_block(mask);
    int sblk = blk - 224, b = sblk >> 4, chunk = sblk & 15;
    __shared__ float hc[64], hsv[64], hst[64];
    __shared__ unsigned int hvn[64], hvx[64], htn[64], htx[64];
    if (tid < 64) {
      hc[tid] = 0.f; hsv[tid] = 0.f; hst[tid] = 0.f;
      hvn[tid] = 0xFFFFFFFFu; hvx[tid] = 0u;
      htn[tid] = 0xFFFFFFFFu; htx[tid] = 0u;
    }
    __syncthreads();
    #pragma unroll
    for (int k = 0; k < 2; k++) {
      int idx = b * SS + chunk * 512 + k * 256 + tid;
      if (mask_at(mask, idx, mm)) {
        int f = fids[idx];
        float val = ldf(values, idx, fm), tim = ldf(times, idx, fm);
        atomicAdd(&hc[f], 1.0f);
        atomicAdd(&hsv[f], val);
        atomicAdd(&hst[f], tim);
        unsigned int vk = fkey(val), tk = fkey(tim);
        atomicMin(&hvn[f], vk); atomicMax(&hvx[f], vk);
        atomicMin(&htn[f], tk); atomicMax(&htx[f], tk);
      }
    }
    __syncthreads();
    if (tid < 64) {
      int base = WS_SP + (sblk * 64 + tid) * 8;
      ws[base + 0] = hc[tid];
      ws[base + 1] = hsv[tid];
      ws[base + 2] = hst[tid];
      ((unsigned int*)ws)[base + 3] = hvn[tid];
      ((unsigned int*)ws)[base + 4] = hvx[tid];
      ((unsigned int*)ws)[base + 5] = htn[tid];
      ((unsigned int*)ws)[base + 6] = htx[tid];
    }
  } else {
    int zblk = blk - 352;
    for (int i = zblk * 256 + tid; i < 14336; i += 2048) ws[WS_CSUM + i] = 0.f;
    if (zblk == 1 && tid < 16) ws[WS_ACC + tid] = 0.f;   // acc[8] + cnt[8]
    if (zblk == 0) {
      int fm = detect_fm_block(times);
      int mm = detect_mm_block(mask);
      if (tid == 0) { ((int*)ws)[0] = fm; ((int*)ws)[1] = mm; }
    }
  }
}

// K2: fold a/c/d through wq/wk/wv (24 blocks) + embedding tables (192 blocks).
__global__ void __launch_bounds__(256) k_pre(const void* wq, const void* wk,
                                             const void* wv, const void* bk,
                                             const void* bv, const void* var_emb,
                                             float* ws) {
  int fm = ((const int*)ws)[0];
  int blk = blockIdx.x, tid = threadIdx.x;
  if (blk < 24) {
    int X = blk >> 3, dg = blk & 7;
    const void* w = (X == 0) ? wq : (X == 1) ? wk : wv;
    __shared__ float sha[224], shc[224], shd[224];
    if (tid < 224) {
      sha[tid] = ws[WS_A + tid];
      shc[tid] = ws[WS_C + tid];
      shd[tid] = ws[WS_D + tid];
    }
    __syncthreads();
    int dsub = tid & 31, jg = tid >> 5;
    int d = dg * 32 + dsub;
    float sa = 0.f, sc = 0.f, sd = 0.f;
    #pragma unroll 4
    for (int jj = 0; jj < 28; jj++) {
      int j = jg * 28 + jj;
      float ww = ldf(w, (32 + j) * 256 + d, fm);
      sa += sha[j] * ww; sc += shc[j] * ww; sd += shd[j] * ww;
    }
    __shared__ float ps[3][8][32];
    ps[0][jg][dsub] = sa; ps[1][jg][dsub] = sc; ps[2][jg][dsub] = sd;
    __syncthreads();
    if (tid < 32) {
      float ra = 0.f, rc = 0.f, rd = 0.f;
      #pragma unroll
      for (int g = 0; g < 8; g++) {
        ra += ps[0][g][tid]; rc += ps[1][g][tid]; rd += ps[2][g][tid];
      }
      int dd = dg * 32 + tid;
      if (X == 1) rd += ldf(bk, dd, fm);
      if (X == 2) rd += ldf(bv, dd, fm);
      int base = (X == 0) ? WS_AQ : (X == 1) ? WS_AK : WS_AV;
      ws[base + dd] = ra;
      ws[base + 256 + dd] = rc;
      ws[base + 512 + dd] = rd;
    }
  } else {
    int idx = blk - 24, X = idx >> 6, v = idx & 63, d = tid;
    const void* w = (X == 0) ? wq : (X == 1) ? wk : wv;
    float s = 0.f;
    #pragma unroll 8
    for (int i = 0; i < 32; i++)
      s += ldf(var_emb, v * 32 + i, fm) * ldf(w, i * 256 + d, fm);
    int base = (X == 0) ? WS_WQE : (X == 1) ? WS_WKE : WS_WVE;
    ws[base + v * 256 + d] = s;
  }
}

// K3: per-(b,v) affine score coefficients, log2e-prescaled, + box max m.
//     Empty variates contribute ctx directly into CSUM here. (16 stat slices now.)
__global__ void __launch_bounds__(256) k_coef(const void* values, const void* times,
                                              const int* fids, const void* bq,
                                              float* ws) {
  int fm = ((const int*)ws)[0];
  int bv = blockIdx.x, b = bv >> 6, v = bv & 63;
  int tid = threadIdx.x, h = tid >> 5;
  __shared__ float sp[16][8];
  if (tid < 128) {
    int sl = tid >> 3, c = tid & 7;
    sp[sl][c] = ws[WS_SP + ((b * 16 + sl) * 64 + v) * 8 + c];
  }
  __syncthreads();
  float cT = 0.f, svT = 0.f, stT = 0.f;
  unsigned int vnk = 0xFFFFFFFFu, vxk = 0u, tnk = 0xFFFFFFFFu, txk = 0u;
  #pragma unroll
  for (int sl = 0; sl < 16; sl++) {
    cT += sp[sl][0]; svT += sp[sl][1]; stT += sp[sl][2];
    unsigned int a3 = __float_as_uint(sp[sl][3]);
    unsigned int a4 = __float_as_uint(sp[sl][4]);
    unsigned int a5 = __float_as_uint(sp[sl][5]);
    unsigned int a6 = __float_as_uint(sp[sl][6]);
    vnk = min(vnk, a3); vxk = max(vxk, a4);
    tnk = min(tnk, a5); txk = max(txk, a6);
  }
  if (cT == 0.f) {
    int f0 = fids[b * SS];
    float v0 = ldf(values, b * SS, fm), t0 = ldf(times, b * SS, fm);
    float ctx = ws[WS_WVE + f0 * 256 + tid] + ws[WS_DV + tid]
              + v0 * ws[WS_AV + tid] + t0 * ws[WS_CV + tid];
    atomicAdd(&ws[WS_CSUM + b * 256 + tid], ctx);
    return;
  }
  float inv = 1.0f / cT, mv = svT * inv, mt = stT * inv;
  float qv = ldf(bq, tid, fm) + ws[WS_WQE + v * 256 + tid]
           + mv * ws[WS_AQ + tid] + mt * ws[WS_CQ + tid] + ws[WS_DQ + tid];
  qv *= 0.17677669529663687f * 1.4426950408889634f;  // 1/sqrt(32) * log2(e)
  float pA = qv * (ws[WS_WKE + v * 256 + tid] + ws[WS_DK + tid]);
  float pB = qv * ws[WS_AK + tid];
  float pC = qv * ws[WS_CK + tid];
  #pragma unroll
  for (int off = 16; off >= 1; off >>= 1) {
    pA += __shfl_xor(pA, off);
    pB += __shfl_xor(pB, off);
    pC += __shfl_xor(pC, off);
  }
  if ((tid & 31) == 0) {
    float vmn = funkey(vnk), vmx = funkey(vxk);
    float tmn = funkey(tnk), tmx = funkey(txk);
    float m = pA + fmaxf(pB * vmn, pB * vmx) + fmaxf(pC * tmn, pC * tmx);
    int base = WS_COEF + (bv * 8 + h) * 4;
    ws[base + 0] = pA; ws[base + 1] = pB; ws[base + 2] = pC; ws[base + 3] = m;
  }
}

// K4: segmented-accumulation scan. 256 blocks (32 per b-row, 256 elem each,
// 1 elem/thread — full-CU coverage vs 128 blocks before).
__global__ void __launch_bounds__(256) k_accum(const void* values, const void* times,
                                               const int* fids, const void* mask,
                                               float* ws) {
  int fm = ((const int*)ws)[0], mm = ((const int*)ws)[1];
  int blk = blockIdx.x, tid = threadIdx.x;
  int b = blk >> 5, chunk = blk & 31;
  __shared__ float co[64 * 36];    // padded: v*36 + h*4 + c  (bank spread)
  __shared__ float bins[64 * 25];  // padded: v*25 + h*3 + c
  for (int i = tid; i < 2048; i += 256) {
    int v = i >> 5, r = i & 31;
    co[v * 36 + r] = ws[WS_COEF + b * 2048 + i];
  }
  for (int i = tid; i < 1600; i += 256) bins[i] = 0.f;
  __syncthreads();
  {
    int idx = b * SS + chunk * 256 + tid;
    if (mask_at(mask, idx, mm)) {
      int f = fids[idx];
      float val = ldf(values, idx, fm), tim = ldf(times, idx, fm);
      #pragma unroll
      for (int h = 0; h < 8; h++) {
        int cb = f * 36 + h * 4;
        float w = exp2f(co[cb] + val * co[cb + 1] + tim * co[cb + 2] - co[cb + 3]);
        int bb = f * 25 + h * 3;
        atomicAdd(&bins[bb], w);
        atomicAdd(&bins[bb + 1], w * val);
        atomicAdd(&bins[bb + 2], w * tim);
      }
    }
  }
  __syncthreads();
  for (int i = tid; i < 1536; i += 256) {
    int f = i / 24, r = i - f * 24;
    float x = bins[f * 25 + r];
    if (x != 0.f) atomicAdd(&ws[WS_BINS + b * 1536 + i], x);
  }
}

// K5: normalize bins, sum ctx over v, then f@wo+bo -> MLP -> out.  (v0 verbatim)
__global__ void __launch_bounds__(1024) k_fin(const void* wo, const void* bo,
                                              const void* cw1, const void* cb1,
                                              const void* cw2, const void* cb2,
                                              float* ws, void* out) {
  int fm = ((const int*)ws)[0];
  int b = blockIdx.x, tid = threadIdx.x;
  __shared__ float aa[64][9], tt[64][9], ne[64];
  __shared__ float ps[4][256], cs[256], fv[256], pr[16];
  if (tid < 512) {
    int v = tid >> 3, h = tid & 7;
    int base = WS_BINS + b * 1536 + v * 24 + h * 3;
    float W = ws[base], WV = ws[base + 1], WT = ws[base + 2];
    float iW = (W > 0.f) ? 1.0f / W : 0.f;
    aa[v][h] = WV * iW; tt[v][h] = WT * iW;
    if (h == 0) ne[v] = (W > 0.f) ? 1.f : 0.f;
  }
  __syncthreads();
  int d = tid & 255, vg = tid >> 8, h = d >> 5;
  float accP = 0.f, accA = 0.f, accT = 0.f, accN = 0.f;
  #pragma unroll 4
  for (int k = 0; k < 16; k++) {
    int v = vg * 16 + k;
    float nef = ne[v];
    accP += nef * ws[WS_WVE + v * 256 + d];
    accA += aa[v][h];    // zero for empty v
    accT += tt[v][h];
    accN += nef;
  }
  ps[vg][d] = accP + accN * ws[WS_DV + d] + accA * ws[WS_AV + d] + accT * ws[WS_CV + d];
  __syncthreads();
  if (tid < 256)
    cs[tid] = (ws[WS_CSUM + b * 256 + tid] + ps[0][tid] + ps[1][tid]
             + ps[2][tid] + ps[3][tid]) * (1.0f / 64.0f);
  __syncthreads();
  float s = 0.f;
  #pragma unroll 8
  for (int k = 0; k < 64; k++) {
    int i = vg * 64 + k;
    s += cs[i] * ldf(wo, i * 256 + d, fm);
  }
  ps[vg][d] = s;
  __syncthreads();
  if (tid < 256) fv[tid] = ps[0][tid] + ps[1][tid] + ps[2][tid] + ps[3][tid]
                         + ldf(bo, tid, fm);
  __syncthreads();
  float t2 = 0.f;
  #pragma unroll 8
  for (int k = 0; k < 64; k++) {
    int i = vg * 64 + k;
    t2 += fv[i] * ldf(cw1, i * 256 + d, fm);
  }
  ps[vg][d] = t2;
  __syncthreads();
  float p = 0.f;
  if (tid < 256) {
    float t = ps[0][tid] + ps[1][tid] + ps[2][tid] + ps[3][tid] + ldf(cb1, tid, fm);
    t = fmaxf(t, 0.f);
    p = t * ldf(cw2, tid, fm);
  }
  #pragma unroll
  for (int off = 32; off >= 1; off >>= 1) p += __shfl_xor(p, off);
  if ((tid & 63) == 0) pr[tid >> 6] = p;
  __syncthreads();
  if (tid == 0) {
    float o = ldf(cb2, 0, fm);
    #pragma unroll
    for (int wgi = 0; wgi < 16; wgi++) o += pr[wgi];
    if (fm) {
      unsigned int x = __float_as_uint(o);
      unsigned int r = (x + 0x7FFFu + ((x >> 16) & 1u)) >> 16;  // RNE
      ((unsigned short*)out)[b] = (unsigned short)r;
    } else {
      ((float*)out)[b] = o;
    }
  }
}

extern "C" void kernel_launch(void* const* d_in, const int* in_sizes, int n_in,
                              void* d_out, int out_size, void* d_ws, size_t ws_size,
                              hipStream_t stream) {
  const void* times   = d_in[0];
  const int*  fids    = (const int*)d_in[1];
  const void* values  = d_in[2];
  const void* vmask   = d_in[3];
  const void* me_w    = d_in[4];
  const void* me_b    = d_in[5];
  const void* var_emb = d_in[6];
  const void* time_w  = d_in[7];
  const void* time_b  = d_in[8];
  const void* agg_w   = d_in[9];
  const void* agg_b   = d_in[10];
  const void* wq = d_in[11]; const void* bq = d_in[12];
  const void* wk = d_in[13]; const void* bk = d_in[14];
  const void* wv = d_in[15]; const void* bv = d_in[16];
  const void* wo = d_in[17]; const void* bo = d_in[18];
  const void* cw1 = d_in[19]; const void* cb1 = d_in[20];
  const void* cw2 = d_in[21]; const void* cb2 = d_in[22];
  float* ws = (float*)d_ws;

  k_front<<<360, 256, 0, stream>>>(times, values, fids, vmask,
                                   me_w, me_b, time_w, time_b, agg_w, agg_b, ws);
  k_pre<<<216, 256, 0, stream>>>(wq, wk, wv, bk, bv, var_emb, ws);
  k_coef<<<512, 256, 0, stream>>>(values, times, fids, bq, ws);
  k_accum<<<256, 256, 0, stream>>>(values, times, fids, vmask, ws);
  k_fin<<<8, 1024, 0, stream>>>(wo, bo, cw1, cb1, cw2, cb2, ws, d_out);
}